// Round 17
// baseline (60.496 us; speedup 1.0000x reference)
//
#include <hip/hip_runtime.h>
#include <hip/hip_bf16.h>

#define B_ 32
#define L_ 512
#define H_ 1024
#define E_ 8
#define R_ 16

typedef float f32x4 __attribute__((ext_vector_type(4)));
typedef __bf16 bf16x8 __attribute__((ext_vector_type(8)));
typedef __bf16 bf16x4 __attribute__((ext_vector_type(4)));

static __device__ __forceinline__ __bf16 f2b(float f) { return (__bf16)f; }

static __device__ __forceinline__ f32x4 MFMA(bf16x8 a, bf16x8 b, f32x4 c) {
  return __builtin_amdgcn_mfma_f32_16x16x32_bf16(a, b, c, 0, 0, 0);
}

#define GLB_AS(p) ((const __attribute__((address_space(1))) void*)(p))
#define LDS_AS(p) ((__attribute__((address_space(3))) void*)(p))

// ---------------- prep: f32 weights -> bf16 in ws; + gates -----------------
__global__ __launch_bounds__(256) void moe_prep_kernel(
    const float* __restrict__ x, const float* __restrict__ rw,
    const float* __restrict__ ldown, const float* __restrict__ lup,
    __bf16* __restrict__ ldb, __bf16* __restrict__ lub,
    float* __restrict__ gws)
{
  const int bid = blockIdx.x;
  if (bid < 256) {                          // weight conversion: 2x131072 f32
    const int base = bid * 1024 + threadIdx.x * 4;
    const float* src; __bf16* dst; int off;
    if (base < 131072) { src = ldown; dst = ldb; off = base; }
    else               { src = lup;   dst = lub; off = base - 131072; }
    float4 v = *(const float4*)(src + off);
    bf16x4 bv = { f2b(v.x), f2b(v.y), f2b(v.z), f2b(v.w) };
    *(bf16x4*)(dst + off) = bv;
    return;
  }
  const int b = bid - 256;
  const int t = threadIdx.x;
  const int e = t >> 5, s = t & 31;
  const float* cls = x + (size_t)b * L_ * H_;
  const float* w   = rw + (size_t)e * H_;
  float p = 0.f;
#pragma unroll
  for (int c = s; c < 256; c += 32) {
    float4 xv = *(const float4*)(cls + 4 * c);
    float4 wv = *(const float4*)(w + 4 * c);
    p += xv.x * wv.x + xv.y * wv.y + xv.z * wv.z + xv.w * wv.w;
  }
#pragma unroll
  for (int off = 16; off; off >>= 1) p += __shfl_down(p, off, 32);
  __shared__ float logits[E_];
  if (s == 0) logits[e] = p;
  __syncthreads();
  if (t == 0) {
    float m0 = -1e30f; int i0 = 0;
    for (int j = 0; j < E_; ++j) if (logits[j] > m0) { m0 = logits[j]; i0 = j; }
    float m1 = -1e30f; int i1 = 0;
    for (int j = 0; j < E_; ++j) if (j != i0 && logits[j] > m1) { m1 = logits[j]; i1 = j; }
    float eb = expf(m1 - m0), inv = 1.f / (1.f + eb);
    gws[b * 4 + 0] = inv;
    gws[b * 4 + 1] = eb * inv;
    ((int*)gws)[b * 4 + 2] = i0;
    ((int*)gws)[b * 4 + 3] = i1;
  }
}

// ---------------- gates-only fallback (no-ws path) -------------------------
__global__ __launch_bounds__(256) void moe_gates_kernel(
    const float* __restrict__ x, const float* __restrict__ rw,
    float* __restrict__ gws)
{
  const int b = blockIdx.x;
  const int t = threadIdx.x;
  const int e = t >> 5, s = t & 31;
  const float* cls = x + (size_t)b * L_ * H_;
  const float* w   = rw + (size_t)e * H_;
  float p = 0.f;
#pragma unroll
  for (int c = s; c < 256; c += 32) {
    float4 xv = *(const float4*)(cls + 4 * c);
    float4 wv = *(const float4*)(w + 4 * c);
    p += xv.x * wv.x + xv.y * wv.y + xv.z * wv.z + xv.w * wv.w;
  }
#pragma unroll
  for (int off = 16; off; off >>= 1) p += __shfl_down(p, off, 32);
  __shared__ float logits[E_];
  if (s == 0) logits[e] = p;
  __syncthreads();
  if (t == 0) {
    float m0 = -1e30f; int i0 = 0;
    for (int j = 0; j < E_; ++j) if (logits[j] > m0) { m0 = logits[j]; i0 = j; }
    float m1 = -1e30f; int i1 = 0;
    for (int j = 0; j < E_; ++j) if (j != i0 && logits[j] > m1) { m1 = logits[j]; i1 = j; }
    float eb = expf(m1 - m0), inv = 1.f / (1.f + eb);
    gws[b * 4 + 0] = inv;
    gws[b * 4 + 1] = eb * inv;
    ((int*)gws)[b * 4 + 2] = i0;
    ((int*)gws)[b * 4 + 3] = i1;
  }
}

// ---------------- main: persistent 4-tile pipeline, counted vmcnt ----------
// 256 blocks (1/CU), 4 tiles each. Double-buffered f32 LDS x-tile staged via
// global_load_lds (DMA). Tile t+1's stage is issued BEFORE tile t's compute;
// raw s_barrier + "s_waitcnt vmcnt(8)" keep those 8 loads/wave in flight
// across ALL of tile t's barriers (T3/T4: never drain vmcnt in the loop).
// Bank conflicts: source pre-swizzled byte^=(row&7)<<4, same XOR on reads.
// Residual + output stay f32 in LDS (exact residual); epilogue streams rows.
template<int BW>
__global__ __launch_bounds__(512, 1) void moe_pipe_kernel(
    const float* __restrict__ x,
    const __bf16* __restrict__ ldb, const __bf16* __restrict__ lub,
    const float* __restrict__ ldf, const float* __restrict__ luf,
    const float* __restrict__ gws, float* __restrict__ out)
{
  __shared__ float  xsf[2][16][1024];       // 131,072 B (two f32 tiles)
  __shared__ float  dgf[2][16][16];         //   2,048 B (atomic K-reduce)
  __shared__ __bf16 dg[16][40];             //   1,280 B (gated bf16 D)

  const int t    = threadIdx.x;
  const int w    = t >> 6;                  // 0..7
  const int lane = t & 63;
  const int gq   = lane >> 4;
  const int r16  = lane & 15;

  ((float*)dgf)[t] = 0.f;                   // visible after first wait+barrier

  const int tile0 = blockIdx.x * 4;

  auto STAGE = [&](int tl, int bufi) {      // wave w stages rows 2w, 2w+1
    const int bb = tl >> 5, ll = (tl & 31) * 16;
    const char* base = (const char*)(x + ((size_t)bb * L_ + ll) * H_);
#pragma unroll
    for (int i = 0; i < 8; ++i) {
      const int row = 2 * w + (i >> 2);
      const unsigned off = (unsigned)(((i & 3) << 10) | (lane << 4))
                         ^ (unsigned)((row & 7) << 4);     // pre-swizzled src
      const char* g = base + (size_t)row * 4096 + off;
      char* l = (char*)&xsf[bufi][0][0] + (w << 13) + (i << 10);  // linear dst
      __builtin_amdgcn_global_load_lds(GLB_AS(g), LDS_AS(l), 16, 0, 0);
    }
  };

  STAGE(tile0, 0);

  const unsigned swz = (unsigned)((r16 & 7) << 4);

#pragma unroll 1
  for (int it = 0; it < 4; ++it) {
    const int tl  = tile0 + it;
    const int cur = it & 1;

    if (it < 3) {
      STAGE(tl + 1, cur ^ 1);               // 8 loads/wave stay in flight
      asm volatile("s_waitcnt vmcnt(8) lgkmcnt(0)" ::: "memory");
    } else {
      asm volatile("s_waitcnt vmcnt(0) lgkmcnt(0)" ::: "memory");
    }
    __builtin_amdgcn_s_barrier();           // buf[cur] ready for all waves

    const int b  = tl >> 5;
    const int l0 = (tl & 31) * 16;
    const float g0 = gws[b * 4 + 0];
    const float g1 = gws[b * 4 + 1];
    const int   e0 = ((const int*)gws)[b * 4 + 2];
    const int   e1 = ((const int*)gws)[b * 4 + 3];

    char* xrow = (char*)&xsf[cur][0][0] + (r16 << 12);   // lane's swizzled row

    // ---- phase A: wave w covers K slice [w*128,(w+1)*128) -----------------
    f32x4 acc0 = {0.f, 0.f, 0.f, 0.f};
    f32x4 acc1 = {0.f, 0.f, 0.f, 0.f};
#pragma unroll
    for (int s = 0; s < 4; ++s) {
      const int kl = w * 128 + s * 32 + 4 * gq;
      float4 xlo = *(const float4*)(xrow + (((unsigned)(kl << 2)) ^ swz));
      float4 xhi = *(const float4*)(xrow + (((unsigned)((kl + 16) << 2)) ^ swz));
      bf16x8 xq = { f2b(xlo.x), f2b(xlo.y), f2b(xlo.z), f2b(xlo.w),
                    f2b(xhi.x), f2b(xhi.y), f2b(xhi.z), f2b(xhi.w) };
      bf16x8 wf0, wf1;
      if constexpr (BW) {
        const __bf16* w0p = ldb + ((size_t)e0 * R_ + r16) * H_;
        const __bf16* w1p = ldb + ((size_t)e1 * R_ + r16) * H_;
        bf16x4 a0 = *(const bf16x4*)(w0p + kl);
        bf16x4 a1 = *(const bf16x4*)(w0p + kl + 16);
        bf16x4 b0 = *(const bf16x4*)(w1p + kl);
        bf16x4 b1 = *(const bf16x4*)(w1p + kl + 16);
        wf0 = bf16x8{ a0[0],a0[1],a0[2],a0[3], a1[0],a1[1],a1[2],a1[3] };
        wf1 = bf16x8{ b0[0],b0[1],b0[2],b0[3], b1[0],b1[1],b1[2],b1[3] };
      } else {
        const float* w0p = ldf + ((size_t)e0 * R_ + r16) * H_;
        const float* w1p = ldf + ((size_t)e1 * R_ + r16) * H_;
        float4 alo = *(const float4*)(w0p + kl);
        float4 ahi = *(const float4*)(w0p + kl + 16);
        float4 blo = *(const float4*)(w1p + kl);
        float4 bhi = *(const float4*)(w1p + kl + 16);
        wf0 = bf16x8{ f2b(alo.x), f2b(alo.y), f2b(alo.z), f2b(alo.w),
                      f2b(ahi.x), f2b(ahi.y), f2b(ahi.z), f2b(ahi.w) };
        wf1 = bf16x8{ f2b(blo.x), f2b(blo.y), f2b(blo.z), f2b(blo.w),
                      f2b(bhi.x), f2b(bhi.y), f2b(bhi.z), f2b(bhi.w) };
      }
      acc0 = MFMA(wf0, xq, acc0);
      acc1 = MFMA(wf1, xq, acc1);
    }
#pragma unroll
    for (int j = 0; j < 4; ++j) {           // K-reduce via LDS atomics
      atomicAdd(&dgf[0][r16][4 * gq + j], acc0[j]);
      atomicAdd(&dgf[1][r16][4 * gq + j], acc1[j]);
    }
    asm volatile("s_waitcnt lgkmcnt(0)" ::: "memory");
    __builtin_amdgcn_s_barrier();

    // ---- pack dg + re-zero dgf -------------------------------------------
    if (t < 128) {
      const int e = t >> 6, slot = t & 63;
      const int l  = slot & 15;
      const int p0 = (slot >> 4) * 4;
      const float g = e ? g1 : g0;
#pragma unroll
      for (int j = 0; j < 4; ++j) {
        dg[l][e * 16 + p0 + j] = f2b(dgf[e][l][p0 + j] * g);
        dgf[e][l][p0 + j] = 0.f;
      }
    }
    asm volatile("s_waitcnt lgkmcnt(0)" ::: "memory");
    __builtin_amdgcn_s_barrier();

    // ---- phase B: wave w covers h in [w*128,(w+1)*128); in-place f32 ------
    bf16x8 dfrag;
#pragma unroll
    for (int j = 0; j < 4; ++j) {
      dfrag[j]     = dg[r16][4 * gq + j];       // k=4gq+j      (e0)
      dfrag[4 + j] = dg[r16][16 + 4 * gq + j];  // k=16+4gq+j   (e1)
    }
#pragma unroll
    for (int nt = 0; nt < 8; ++nt) {
      const int h0 = w * 128 + nt * 16;
      const int ha = h0 + r16;
      bf16x8 uf;
      if constexpr (BW) {
        bf16x4 ulo = *(const bf16x4*)(lub + ((size_t)e0 * H_ + ha) * R_ + 4 * gq);
        bf16x4 uhi = *(const bf16x4*)(lub + ((size_t)e1 * H_ + ha) * R_ + 4 * gq);
        uf = bf16x8{ ulo[0],ulo[1],ulo[2],ulo[3], uhi[0],uhi[1],uhi[2],uhi[3] };
      } else {
        float4 ulo = *(const float4*)(luf + ((size_t)e0 * H_ + ha) * R_ + 4 * gq);
        float4 uhi = *(const float4*)(luf + ((size_t)e1 * H_ + ha) * R_ + 4 * gq);
        uf = bf16x8{ f2b(ulo.x), f2b(ulo.y), f2b(ulo.z), f2b(ulo.w),
                     f2b(uhi.x), f2b(uhi.y), f2b(uhi.z), f2b(uhi.w) };
      }
      const unsigned cb = ((unsigned)((h0 + 4 * gq) << 2)) ^ swz;
      float4 rx = *(const float4*)(xrow + cb);          // exact f32 residual
      f32x4 acc = { rx.x, rx.y, rx.z, rx.w };
      acc = MFMA(uf, dfrag, acc);
      *(float4*)(xrow + cb) = *(float4*)&acc;           // in-place, same lane
    }
    asm volatile("s_waitcnt lgkmcnt(0)" ::: "memory");
    __builtin_amdgcn_s_barrier();

    // ---- epilogue: stream whole f32 rows (512B contiguous / instruction) --
    {
      const int row = 2 * w + (lane >> 5);
      const unsigned rswz = (unsigned)((row & 7) << 4);
      const char* lrow = (const char*)&xsf[cur][0][0] + (row << 12);
      float* outrow = out + ((size_t)b * L_ + l0 + row) * H_;
#pragma unroll
      for (int i2 = 0; i2 < 8; ++i2) {
        const unsigned cb = (unsigned)((i2 << 9) | ((lane & 31) << 4));
        float4 v = *(const float4*)(lrow + (cb ^ rswz));
        *(float4*)(outrow + i2 * 128 + (lane & 31) * 4) = v;
      }
    }
    // no trailing barrier: next iteration's STAGE targets buf[cur^1], and
    // buf[cur] rows 2w,2w+1 are re-staged only by wave w itself (it+2),
    // issued wave-locally after this epilogue's reads.
  }
}

extern "C" void kernel_launch(void* const* d_in, const int* in_sizes, int n_in,
                              void* d_out, int out_size, void* d_ws, size_t ws_size,
                              hipStream_t stream) {
  const float* x  = (const float*)d_in[0];
  const float* rw = (const float*)d_in[1];
  const float* ld = (const float*)d_in[2];
  const float* lu = (const float*)d_in[3];
  float* outp = (float*)d_out;

  float*  gws = (float*)d_ws;                         // 512 B
  __bf16* ldb = (__bf16*)((char*)d_ws + 1024);        // 256 KB
  __bf16* lub = ldb + 131072;                         // 256 KB

  if (ws_size >= 1024 + 2 * 131072 * sizeof(__bf16)) {
    hipLaunchKernelGGL(moe_prep_kernel, dim3(256 + B_), dim3(256), 0, stream,
                       x, rw, ld, lu, ldb, lub, gws);
    hipLaunchKernelGGL(moe_pipe_kernel<1>, dim3(256), dim3(512), 0, stream,
                       x, ldb, lub, nullptr, nullptr, gws, outp);
  } else {
    hipLaunchKernelGGL(moe_gates_kernel, dim3(B_), dim3(256), 0, stream,
                       x, rw, gws);
    hipLaunchKernelGGL(moe_pipe_kernel<0>, dim3(256), dim3(512), 0, stream,
                       x, nullptr, nullptr, ld, lu, gws, outp);
  }
}